// Round 8
// baseline (5737.403 us; speedup 1.0000x reference)
//
#include <hip/hip_runtime.h>
#include <cstdint>
#include <cstddef>

// Lessons: (r5) hot atomic counters serialize — keep >=10k counters, <100 ops/ctr.
// (r7) random 256B row-gather over 25.6MB working set leaves FETCH at 2x working-set
//      per reuse-life; fix = dest-tiled LDS accumulation + src-swept edge order.

#define DBLK 128   // dests per agg2 block (64KB LDS accumulator)
#define SB   64    // src buckets per dest-block (src >> 11, needs n <= 131072)

typedef short bf16x8 __attribute__((ext_vector_type(8)));
typedef float f32x4 __attribute__((ext_vector_type(4)));

// ---------------- bf16 helpers ----------------
static __device__ __forceinline__ uint32_t f2bf(float x) {
  uint32_t u = __float_as_uint(x);
  return (u + 0x7fffu + ((u >> 16) & 1u)) >> 16;  // RNE
}
static __device__ __forceinline__ uint32_t pack2(float a, float b) {
  return f2bf(a) | (f2bf(b) << 16);
}
static __device__ __forceinline__ float bf_lo(uint32_t u) { return __uint_as_float(u << 16); }
static __device__ __forceinline__ float bf_hi(uint32_t u) { return __uint_as_float(u & 0xffff0000u); }

// ---------------- Threefry-2x32-20, key (0,42) ----------------
static __device__ __forceinline__ uint32_t rotl32(uint32_t v, int d) {
  return (v << d) | (v >> (32 - d));
}

static __device__ __forceinline__ void threefry2x32(uint32_t k0, uint32_t k1,
                                                    uint32_t& x0, uint32_t& x1) {
  uint32_t k2 = k0 ^ k1 ^ 0x1BD11BDAu;
  x0 += k0; x1 += k1;
#define TF_R(r) { x0 += x1; x1 = rotl32(x1, (r)); x1 ^= x0; }
  TF_R(13) TF_R(15) TF_R(26) TF_R(6)
  x0 += k1; x1 += k2 + 1u;
  TF_R(17) TF_R(29) TF_R(16) TF_R(24)
  x0 += k2; x1 += k0 + 2u;
  TF_R(13) TF_R(15) TF_R(26) TF_R(6)
  x0 += k0; x1 += k1 + 3u;
  TF_R(17) TF_R(29) TF_R(16) TF_R(24)
  x0 += k1; x1 += k2 + 4u;
  TF_R(13) TF_R(15) TF_R(26) TF_R(6)
  x0 += k2; x1 += k0 + 5u;
#undef TF_R
}

// ---------------- graph preprocessing ----------------
__global__ void init2_kernel(int* cnt, int* cnt_k, int n, int nkeys) {
  int i = blockIdx.x * blockDim.x + threadIdx.x;
  if (i < n) cnt[i] = 0;
  if (i < nkeys) cnt_k[i] = 0;
}

// degree count + within-(destblock,srcbucket) rank
__global__ void count2_kernel(const int* __restrict__ fs, const int* __restrict__ fd,
                              int* __restrict__ cnt, int* __restrict__ cnt_k,
                              int* __restrict__ rank_k, int e) {
  int i = blockIdx.x * blockDim.x + threadIdx.x;
  if (i < e) {
    int d = fd[i];
    atomicAdd(&cnt[d], 1);
    int key = (d >> 7) * SB + (fs[i] >> 11);
    rank_k[i] = atomicAdd(&cnt_k[key], 1);
  }
}

__global__ void dis_kernel(const int* __restrict__ cnt, float* __restrict__ dis, int n) {
  int i = blockIdx.x * blockDim.x + threadIdx.x;
  if (i < n) dis[i] = 1.0f / sqrtf((float)(cnt[i] + 1));  // deg includes self-loop
}

// generic exclusive scan (m elements) — same structure as before
__global__ void scanA_kernel(const int* __restrict__ cnt, int* __restrict__ off,
                             int* __restrict__ bsum, int m) {
  __shared__ int s[256];
  int t = threadIdx.x;
  int i = blockIdx.x * 256 + t;
  int v = (i < m) ? cnt[i] : 0;
  s[t] = v;
  __syncthreads();
  for (int d = 1; d < 256; d <<= 1) {
    int add = (t >= d) ? s[t - d] : 0;
    __syncthreads();
    s[t] += add;
    __syncthreads();
  }
  if (i < m) off[i] = s[t] - v;  // exclusive
  if (t == 255) bsum[blockIdx.x] = s[255];
}

__global__ void scanB_kernel(const int* __restrict__ bsum, int* __restrict__ boff,
                             int nb, int* __restrict__ off, int m) {
  __shared__ int s[512];
  int t = threadIdx.x;
  int v = (t < nb) ? bsum[t] : 0;
  s[t] = v;
  __syncthreads();
  for (int d = 1; d < 512; d <<= 1) {
    int add = (t >= d) ? s[t - d] : 0;
    __syncthreads();
    s[t] += add;
    __syncthreads();
  }
  if (t < nb) boff[t] = s[t] - v;
  if (t == nb - 1) off[m] = s[t];  // total = E
}

__global__ void scanC2_kernel(int* __restrict__ off, const int* __restrict__ boff, int m) {
  int i = blockIdx.x * 256 + threadIdx.x;
  if (i < m) off[i] += boff[blockIdx.x];
}

// scatter into key-sorted edge list: {src | dlocal<<17, w}
__global__ void fill2_kernel(const int* __restrict__ fs, const int* __restrict__ fd,
                             const int* __restrict__ rank_k, const int* __restrict__ koff,
                             const float* __restrict__ dis,
                             uint2* __restrict__ csr2, int e) {
  int i = blockIdx.x * blockDim.x + threadIdx.x;
  if (i < e) {
    int s = fs[i], d = fd[i];
    int key = (d >> 7) * SB + (s >> 11);
    csr2[koff[key] + rank_k[i]] =
        make_uint2((uint32_t)s | ((uint32_t)(d & (DBLK - 1)) << 17),
                   __float_as_uint(dis[s] * dis[d]));
  }
}

// h0 = query[batch] * x -> bf16 hb (residual lives in bf16)
__global__ void h0_kernel(const float* __restrict__ x, const float* __restrict__ query,
                          const int* __restrict__ batch, uint32_t* __restrict__ hb, int n) {
  int i = blockIdx.x * blockDim.x + threadIdx.x;  // one bf16x2 word (2 cols)
  int total = n * 64;
  if (i < total) {
    int node = i >> 6;
    int w = i & 63;
    int b = batch[node];
    float2 xv = ((const float2*)x)[i];
    float2 qv = ((const float2*)query)[b * 64 + w];
    hb[i] = pack2(xv.x * qv.x, xv.y * qv.y);
  }
}

// ---------------- MFMA GEMM (unchanged from round 7) ----------------
template<int BN, int OUT_BF16>
__global__ __launch_bounds__(256)
void mfma_gemm_kernel(const uint32_t* __restrict__ Abf,   // bf16x2 words, row stride 64
                      const float* __restrict__ Wm,       // fp32 [128][BN] row-major
                      const float* __restrict__ bias,     // nullptr or [BN]
                      void* __restrict__ Cout, int nrows) {
  constexpr int CT = BN / 16;
  __shared__ short Wt[2][BN][136];
  const int tid = threadIdx.x;

  for (int q = tid; q < (128 * BN) / 4; q += 256) {
    int el = q * 4;
    int k = el / BN;
    int col = el % BN;
    float4 w4 = *(const float4*)(Wm + el);
    float wv[4] = {w4.x, w4.y, w4.z, w4.w};
#pragma unroll
    for (int j = 0; j < 4; ++j) {
      uint32_t hi = f2bf(wv[j]);
      float hif = __uint_as_float(hi << 16);
      uint32_t lo = f2bf(wv[j] - hif);
      Wt[0][col + j][k] = (short)hi;
      Wt[1][col + j][k] = (short)lo;
    }
  }
  __syncthreads();

  const int wave = tid >> 6;
  const int lane = tid & 63;
  const int lrow = lane & 15;
  const int lk = lane >> 4;
  const int rowbase = blockIdx.x * 256 + wave * 64;
  const uint16_t* Au = (const uint16_t*)Abf;

  f32x4 acc[4][CT];
#pragma unroll
  for (int rt = 0; rt < 4; ++rt)
#pragma unroll
    for (int ct = 0; ct < CT; ++ct) acc[rt][ct] = (f32x4){0.f, 0.f, 0.f, 0.f};

#pragma unroll
  for (int s = 0; s < 4; ++s) {
    bf16x8 a[4];
#pragma unroll
    for (int rt = 0; rt < 4; ++rt) {
      int gr = rowbase + rt * 16 + lrow;
      int gra = (gr < nrows) ? gr : 0;
      a[rt] = *reinterpret_cast<const bf16x8*>(Au + (size_t)gra * 128 + s * 32 + lk * 8);
    }
#pragma unroll
    for (int ct = 0; ct < CT; ++ct) {
      bf16x8 bhi = *reinterpret_cast<const bf16x8*>(&Wt[0][ct * 16 + lrow][s * 32 + lk * 8]);
      bf16x8 blo = *reinterpret_cast<const bf16x8*>(&Wt[1][ct * 16 + lrow][s * 32 + lk * 8]);
#pragma unroll
      for (int rt = 0; rt < 4; ++rt)
        acc[rt][ct] = __builtin_amdgcn_mfma_f32_16x16x32_bf16(a[rt], bhi, acc[rt][ct], 0, 0, 0);
#pragma unroll
      for (int rt = 0; rt < 4; ++rt)
        acc[rt][ct] = __builtin_amdgcn_mfma_f32_16x16x32_bf16(a[rt], blo, acc[rt][ct], 0, 0, 0);
    }
  }

#pragma unroll
  for (int rt = 0; rt < 4; ++rt)
#pragma unroll
    for (int ct = 0; ct < CT; ++ct)
#pragma unroll
      for (int r = 0; r < 4; ++r) {
        int gr = rowbase + rt * 16 + lk * 4 + r;
        if (gr >= nrows) continue;
        int col = ct * 16 + lrow;
        float v = acc[rt][ct][r];
        if constexpr (OUT_BF16) {
          ((uint16_t*)Cout)[(size_t)gr * BN + col] = (uint16_t)f2bf(v);
        } else {
          v += bias[col];
          uint32_t x0 = 0u, x1 = (uint32_t)gr * (uint32_t)BN + (uint32_t)col;
          threefry2x32(0u, 42u, x0, x1);
          uint32_t bits = x0 ^ x1;
          float u = __uint_as_float((bits >> 9) | 0x3F800000u) - 1.0f;
          ((float*)Cout)[(size_t)gr * BN + col] = (u < 0.8f) ? (v / 0.8f) : 0.0f;
        }
      }
}

// ---------------- agg2: dest-tiled LDS accumulation, src-swept edges ----------------
// One block per 128 dests. Edges pre-sorted by (destblock, srcbucket) so all
// concurrent blocks sweep src-space together -> gather band stays L2-resident.
__global__ __launch_bounds__(256)
void agg2_kernel(const uint32_t* __restrict__ hwb, uint32_t* __restrict__ hb,
                 const float* __restrict__ bias, const int* __restrict__ koff,
                 const uint2* __restrict__ csr2, const float* __restrict__ dis,
                 int relu, int n) {
  __shared__ float acc[DBLK * 128];            // 64KB fp32 accumulator
  const int tid = threadIdx.x;
  const int blk = blockIdx.x;
  for (int q = tid; q < DBLK * 128 / 4; q += 256)
    ((float4*)acc)[q] = make_float4(0.f, 0.f, 0.f, 0.f);
  __syncthreads();

  const int lane = tid & 63, wave = tid >> 6;
  const int e0 = koff[blk * SB], e1 = koff[(blk + 1) * SB];
  const int nch = (e1 - e0 + 7) >> 3;          // chunks of 8, interleaved across waves
  for (int ch = wave; ch < nch; ch += 4) {
    int ib = e0 + ch * 8;
    int m = min(8, e1 - ib);
    if (m == 8) {
      uint2 c[8];
      uint32_t r[8];
#pragma unroll
      for (int j = 0; j < 8; ++j) c[j] = csr2[ib + j];          // wave-uniform -> broadcast
#pragma unroll
      for (int j = 0; j < 8; ++j) r[j] = hwb[(size_t)(c[j].x & 0x1ffffu) * 64 + lane];
#pragma unroll
      for (int j = 0; j < 8; ++j) {
        int dl = (int)(c[j].x >> 17);
        float w = __uint_as_float(c[j].y);
        atomicAdd(&acc[dl * 128 + 2 * lane],     w * bf_lo(r[j]));
        atomicAdd(&acc[dl * 128 + 2 * lane + 1], w * bf_hi(r[j]));
      }
    } else {
      for (int j = 0; j < m; ++j) {
        uint2 c = csr2[ib + j];
        uint32_t r = hwb[(size_t)(c.x & 0x1ffffu) * 64 + lane];
        int dl = (int)(c.x >> 17);
        float w = __uint_as_float(c.y);
        atomicAdd(&acc[dl * 128 + 2 * lane],     w * bf_lo(r));
        atomicAdd(&acc[dl * 128 + 2 * lane + 1], w * bf_hi(r));
      }
    }
  }
  __syncthreads();

  // epilogue: hb[v] = maybe_relu(bias + res + dis^2*hwb[v] + acc)
  const int base = blk * DBLK;
  for (int q = tid; q < DBLK * 64; q += 256) {
    int row = q >> 6, wc = q & 63;
    int v = base + row;
    if (v >= n) continue;
    float dv = dis[v];
    float sw = dv * dv;
    uint32_t self = hwb[(size_t)v * 64 + wc];
    uint32_t res = hb[(size_t)v * 64 + wc];
    float2 bb = ((const float2*)bias)[wc];
    float ax = bb.x + bf_lo(res) + sw * bf_lo(self) + acc[row * 128 + 2 * wc];
    float ay = bb.y + bf_hi(res) + sw * bf_hi(self) + acc[row * 128 + 2 * wc + 1];
    if (relu) { ax = fmaxf(ax, 0.f); ay = fmaxf(ay, 0.f); }
    hb[(size_t)v * 64 + wc] = pack2(ax, ay);
  }
}

// ---------------- launch ----------------
extern "C" void kernel_launch(void* const* d_in, const int* in_sizes, int n_in,
                              void* d_out, int out_size, void* d_ws, size_t ws_size,
                              hipStream_t stream) {
  const float* x     = (const float*)d_in[0];
  const float* query = (const float*)d_in[1];
  const int*   batch = (const int*)d_in[2];
  const int*   eidx  = (const int*)d_in[3];
  const float* W[4]  = {(const float*)d_in[4], (const float*)d_in[6],
                        (const float*)d_in[8], (const float*)d_in[10]};
  const float* bv[4] = {(const float*)d_in[5], (const float*)d_in[7],
                        (const float*)d_in[9], (const float*)d_in[11]};
  const float* Wc = (const float*)d_in[12];
  const float* bc = (const float*)d_in[13];
  float* out = (float*)d_out;

  const int n = in_sizes[2];       // 100000 (key packing needs n <= 131072)
  const int e = in_sizes[3] / 2;   // 1600000
  const int* fs = eidx;            // edge_index[0] = sources
  const int* fd = eidx + e;        // edge_index[1] = targets (aggregation index)

  const int nblk = (n + DBLK - 1) / DBLK;      // 782 dest blocks
  const int nkeys = nblk * SB;                 // 50048

  char* p = (char*)d_ws;
  auto carve = [&](size_t bytes) -> void* {
    void* r = (void*)p;
    p += (bytes + 255) & ~(size_t)255;
    return r;
  };
  const int kscan = (nkeys + 255) / 256;       // 196 (<= 512 for scanB)
  int*      cnt     = (int*)carve((size_t)n * 4);
  int*      cnt_k   = (int*)carve((size_t)nkeys * 4);
  int*      koff    = (int*)carve((size_t)(nkeys + 1) * 4);
  int*      bsum    = (int*)carve((size_t)kscan * 4);
  int*      boff    = (int*)carve((size_t)kscan * 4);
  int*      rank_k  = (int*)carve((size_t)e * 4);
  float*    dis     = (float*)carve((size_t)n * 4);
  uint2*    csr2    = (uint2*)carve((size_t)e * 8);
  uint32_t* hb      = (uint32_t*)carve((size_t)n * 64 * 4);     // bf16 h (residual + GEMM in)
  uint32_t* hwb     = (uint32_t*)carve((size_t)n * 64 * 4);     // bf16 h@W (gather src)

  const int eb = (e + 255) / 256;
  const int nb_init = (n > nkeys ? n : nkeys);

  init2_kernel<<<(nb_init + 255) / 256, 256, 0, stream>>>(cnt, cnt_k, n, nkeys);
  count2_kernel<<<eb, 256, 0, stream>>>(fs, fd, cnt, cnt_k, rank_k, e);
  dis_kernel<<<(n + 255) / 256, 256, 0, stream>>>(cnt, dis, n);
  scanA_kernel<<<kscan, 256, 0, stream>>>(cnt_k, koff, bsum, nkeys);
  scanB_kernel<<<1, 512, 0, stream>>>(bsum, boff, kscan, koff, nkeys);
  scanC2_kernel<<<kscan, 256, 0, stream>>>(koff, boff, nkeys);
  fill2_kernel<<<eb, 256, 0, stream>>>(fs, fd, rank_k, koff, dis, csr2, e);
  h0_kernel<<<(n * 64 + 255) / 256, 256, 0, stream>>>(x, query, batch, hb, n);

  const int gblk = (n + 255) / 256;
  for (int l = 0; l < 4; ++l) {
    mfma_gemm_kernel<128, 1><<<gblk, 256, 0, stream>>>(hb, W[l], nullptr, hwb, n);
    agg2_kernel<<<nblk, 256, 0, stream>>>(hwb, hb, bv[l], koff, csr2, dis,
                                          (l < 3) ? 1 : 0, n);
  }
  mfma_gemm_kernel<64, 0><<<gblk, 256, 0, stream>>>(hb, Wc, bc, out, n);
}

// Round 9
// 558.574 us; speedup vs baseline: 10.2715x; 10.2715x over previous
//
#include <hip/hip_runtime.h>
#include <cstdint>
#include <cstddef>

// Lessons: (r5) hot atomic counters serialize — keep counters distributed.
// (r8) LDS-atomic accumulation + 64KB-LDS/1-block-per-CU agg = 10x loss; random
//      gather is L3-served (~3.5 TB/s random-64B ceiling) -> only fewer bytes help.
// r9: agg reverted to r7 structure; gather rows in fp8 e4m3 (residual stays bf16);
//     csr packed to 4B/edge (src 17b | w-bf15 15b).

typedef short bf16x8 __attribute__((ext_vector_type(8)));
typedef float f32x4 __attribute__((ext_vector_type(4)));

// ---------------- bf16 helpers ----------------
static __device__ __forceinline__ uint32_t f2bf(float x) {
  uint32_t u = __float_as_uint(x);
  return (u + 0x7fffu + ((u >> 16) & 1u)) >> 16;  // RNE
}
static __device__ __forceinline__ uint32_t pack2(float a, float b) {
  return f2bf(a) | (f2bf(b) << 16);
}
static __device__ __forceinline__ float bf_lo(uint32_t u) { return __uint_as_float(u << 16); }
static __device__ __forceinline__ float bf_hi(uint32_t u) { return __uint_as_float(u & 0xffff0000u); }

// ---------------- Threefry-2x32-20, key (0,42) ----------------
static __device__ __forceinline__ uint32_t rotl32(uint32_t v, int d) {
  return (v << d) | (v >> (32 - d));
}

static __device__ __forceinline__ void threefry2x32(uint32_t k0, uint32_t k1,
                                                    uint32_t& x0, uint32_t& x1) {
  uint32_t k2 = k0 ^ k1 ^ 0x1BD11BDAu;
  x0 += k0; x1 += k1;
#define TF_R(r) { x0 += x1; x1 = rotl32(x1, (r)); x1 ^= x0; }
  TF_R(13) TF_R(15) TF_R(26) TF_R(6)
  x0 += k1; x1 += k2 + 1u;
  TF_R(17) TF_R(29) TF_R(16) TF_R(24)
  x0 += k2; x1 += k0 + 2u;
  TF_R(13) TF_R(15) TF_R(26) TF_R(6)
  x0 += k0; x1 += k1 + 3u;
  TF_R(17) TF_R(29) TF_R(16) TF_R(24)
  x0 += k1; x1 += k2 + 4u;
  TF_R(13) TF_R(15) TF_R(26) TF_R(6)
  x0 += k2; x1 += k0 + 5u;
#undef TF_R
}

// ---------------- graph preprocessing (r7 structure) ----------------
__global__ void init_kernel(int* cnt, int n) {
  int i = blockIdx.x * blockDim.x + threadIdx.x;
  if (i < n) cnt[i] = 0;
}

__global__ void count_rank_kernel(const int* __restrict__ fd, int* __restrict__ cnt,
                                  int* __restrict__ rank, int e) {
  int i = blockIdx.x * blockDim.x + threadIdx.x;
  if (i < e) rank[i] = atomicAdd(&cnt[fd[i]], 1);
}

__global__ void scanA_kernel(const int* __restrict__ cnt, int* __restrict__ off,
                             int* __restrict__ bsum, int n) {
  __shared__ int s[256];
  int t = threadIdx.x;
  int i = blockIdx.x * 256 + t;
  int v = (i < n) ? cnt[i] : 0;
  s[t] = v;
  __syncthreads();
  for (int d = 1; d < 256; d <<= 1) {
    int add = (t >= d) ? s[t - d] : 0;
    __syncthreads();
    s[t] += add;
    __syncthreads();
  }
  if (i < n) off[i] = s[t] - v;  // exclusive
  if (t == 255) bsum[blockIdx.x] = s[255];
}

__global__ void scanB_kernel(const int* __restrict__ bsum, int* __restrict__ boff,
                             int nb, int* __restrict__ off, int n) {
  __shared__ int s[512];
  int t = threadIdx.x;
  int v = (t < nb) ? bsum[t] : 0;
  s[t] = v;
  __syncthreads();
  for (int d = 1; d < 512; d <<= 1) {
    int add = (t >= d) ? s[t - d] : 0;
    __syncthreads();
    s[t] += add;
    __syncthreads();
  }
  if (t < nb) boff[t] = s[t] - v;
  if (t == nb - 1) off[n] = s[t];  // total = E
}

__global__ void scanC_kernel(int* __restrict__ off, const int* __restrict__ boff,
                             const int* __restrict__ cnt, float* __restrict__ dis, int n) {
  int i = blockIdx.x * 256 + threadIdx.x;
  if (i < n) {
    off[i] += boff[blockIdx.x];
    dis[i] = 1.0f / sqrtf((float)(cnt[i] + 1));  // deg includes self-loop
  }
}

// atomic-free scatter; packed entry: src(17 bits) | bf16(w)[14:0] << 17  (w>0, <2)
__global__ void fill_kernel(const int* __restrict__ fs, const int* __restrict__ fd,
                            const int* __restrict__ rank, const int* __restrict__ off,
                            const float* __restrict__ dis,
                            uint32_t* __restrict__ csr, int e) {
  int i = blockIdx.x * blockDim.x + threadIdx.x;
  if (i < e) {
    int s = fs[i], d = fd[i];
    uint32_t w15 = f2bf(dis[s] * dis[d]) & 0x7fffu;
    csr[off[d] + rank[i]] = (uint32_t)s | (w15 << 17);
  }
}

// h0 = query[batch] * x -> bf16 hb (residual lives in bf16)
__global__ void h0_kernel(const float* __restrict__ x, const float* __restrict__ query,
                          const int* __restrict__ batch, uint32_t* __restrict__ hb, int n) {
  int i = blockIdx.x * blockDim.x + threadIdx.x;  // one bf16x2 word (2 cols)
  int total = n * 64;
  if (i < total) {
    int node = i >> 6;
    int w = i & 63;
    int b = batch[node];
    float2 xv = ((const float2*)x)[i];
    float2 qv = ((const float2*)query)[b * 64 + w];
    hb[i] = pack2(xv.x * qv.x, xv.y * qv.y);
  }
}

// ---------------- MFMA GEMM: C[nrows,BN] = A_bf16[nrows,128] @ W_f32[128,BN] ----------------
// W split into bf16 hi+lo -> two MFMAs per k-step give ~fp32-grade accuracy.
// OUT_MODE 1: write fp8 e4m3 bytes (gather source). OUT_MODE 0: fp32 +bias +fused dropout.
template<int BN, int OUT_MODE>
__global__ __launch_bounds__(256)
void mfma_gemm_kernel(const uint32_t* __restrict__ Abf,   // bf16x2 words, row stride 64
                      const float* __restrict__ Wm,       // fp32 [128][BN] row-major
                      const float* __restrict__ bias,     // nullptr or [BN]
                      void* __restrict__ Cout, int nrows) {
  constexpr int CT = BN / 16;
  __shared__ short Wt[2][BN][136];
  const int tid = threadIdx.x;

  for (int q = tid; q < (128 * BN) / 4; q += 256) {
    int el = q * 4;
    int k = el / BN;
    int col = el % BN;
    float4 w4 = *(const float4*)(Wm + el);
    float wv[4] = {w4.x, w4.y, w4.z, w4.w};
#pragma unroll
    for (int j = 0; j < 4; ++j) {
      uint32_t hi = f2bf(wv[j]);
      float hif = __uint_as_float(hi << 16);
      uint32_t lo = f2bf(wv[j] - hif);
      Wt[0][col + j][k] = (short)hi;
      Wt[1][col + j][k] = (short)lo;
    }
  }
  __syncthreads();

  const int wave = tid >> 6;
  const int lane = tid & 63;
  const int lrow = lane & 15;
  const int lk = lane >> 4;
  const int rowbase = blockIdx.x * 256 + wave * 64;
  const uint16_t* Au = (const uint16_t*)Abf;

  f32x4 acc[4][CT];
#pragma unroll
  for (int rt = 0; rt < 4; ++rt)
#pragma unroll
    for (int ct = 0; ct < CT; ++ct) acc[rt][ct] = (f32x4){0.f, 0.f, 0.f, 0.f};

#pragma unroll
  for (int s = 0; s < 4; ++s) {
    bf16x8 a[4];
#pragma unroll
    for (int rt = 0; rt < 4; ++rt) {
      int gr = rowbase + rt * 16 + lrow;
      int gra = (gr < nrows) ? gr : 0;
      a[rt] = *reinterpret_cast<const bf16x8*>(Au + (size_t)gra * 128 + s * 32 + lk * 8);
    }
#pragma unroll
    for (int ct = 0; ct < CT; ++ct) {
      bf16x8 bhi = *reinterpret_cast<const bf16x8*>(&Wt[0][ct * 16 + lrow][s * 32 + lk * 8]);
      bf16x8 blo = *reinterpret_cast<const bf16x8*>(&Wt[1][ct * 16 + lrow][s * 32 + lk * 8]);
#pragma unroll
      for (int rt = 0; rt < 4; ++rt)
        acc[rt][ct] = __builtin_amdgcn_mfma_f32_16x16x32_bf16(a[rt], bhi, acc[rt][ct], 0, 0, 0);
#pragma unroll
      for (int rt = 0; rt < 4; ++rt)
        acc[rt][ct] = __builtin_amdgcn_mfma_f32_16x16x32_bf16(a[rt], blo, acc[rt][ct], 0, 0, 0);
    }
  }

  // store: C/D mapping col=lane&15, row=(lane>>4)*4+reg
#pragma unroll
  for (int rt = 0; rt < 4; ++rt)
#pragma unroll
    for (int ct = 0; ct < CT; ++ct)
#pragma unroll
      for (int r = 0; r < 4; ++r) {
        int gr = rowbase + rt * 16 + lk * 4 + r;
        if (gr >= nrows) continue;
        int col = ct * 16 + lrow;
        float v = acc[rt][ct][r];
        if constexpr (OUT_MODE == 1) {
          uint32_t pk = __builtin_amdgcn_cvt_pk_fp8_f32(v, v, 0u, false);
          ((uint8_t*)Cout)[(size_t)gr * BN + col] = (uint8_t)pk;
        } else {
          v += bias[col];
          uint32_t x0 = 0u, x1 = (uint32_t)gr * (uint32_t)BN + (uint32_t)col;
          threefry2x32(0u, 42u, x0, x1);
          uint32_t bits = x0 ^ x1;
          float u = __uint_as_float((bits >> 9) | 0x3F800000u) - 1.0f;
          ((float*)Cout)[(size_t)gr * BN + col] = (u < 0.8f) ? (v / 0.8f) : 0.0f;
        }
      }
}

// ---------------- aggregation: one wave64 per node, fp8 rows, 8-way unroll ----------------
// hb[v] := maybe_relu( bias + hb[v](res,bf16) + dis^2*hw8[v] + sum_edges w*hw8[src] )
__global__ __launch_bounds__(256)
void agg_kernel(const uint8_t* __restrict__ hw8, uint32_t* __restrict__ hb,
                const float* __restrict__ bias,
                const int* __restrict__ off, const uint32_t* __restrict__ csr,
                const float* __restrict__ dis, int relu, int n) {
  int wid = (blockIdx.x * blockDim.x + threadIdx.x) >> 6;
  int lane = threadIdx.x & 63;
  if (wid >= n) return;
  int v = wid;
  float dv = dis[v];
  float sw = dv * dv;
  uint32_t self16 = *(const uint16_t*)(hw8 + (size_t)v * 128 + 2 * lane);
  uint32_t resw = hb[(size_t)v * 64 + lane];
  float2 bb = ((const float2*)bias)[lane];
  float accx = fmaf(sw, __builtin_amdgcn_cvt_f32_fp8(self16, 0), bb.x + bf_lo(resw));
  float accy = fmaf(sw, __builtin_amdgcn_cvt_f32_fp8(self16, 1), bb.y + bf_hi(resw));
  int s0 = off[v], s1 = off[v + 1];
  int i = s0;
  for (; i + 7 < s1; i += 8) {
    uint32_t c[8];
    uint32_t r[8];
#pragma unroll
    for (int j = 0; j < 8; ++j) c[j] = csr[i + j];
#pragma unroll
    for (int j = 0; j < 8; ++j)
      r[j] = *(const uint16_t*)(hw8 + (size_t)(c[j] & 0x1ffffu) * 128 + 2 * lane);
#pragma unroll
    for (int j = 0; j < 8; ++j) {
      float w = __uint_as_float((c[j] >> 17) << 16);
      accx = fmaf(w, __builtin_amdgcn_cvt_f32_fp8(r[j], 0), accx);
      accy = fmaf(w, __builtin_amdgcn_cvt_f32_fp8(r[j], 1), accy);
    }
  }
  for (; i < s1; ++i) {
    uint32_t c = csr[i];
    uint32_t r = *(const uint16_t*)(hw8 + (size_t)(c & 0x1ffffu) * 128 + 2 * lane);
    float w = __uint_as_float((c >> 17) << 16);
    accx = fmaf(w, __builtin_amdgcn_cvt_f32_fp8(r, 0), accx);
    accy = fmaf(w, __builtin_amdgcn_cvt_f32_fp8(r, 1), accy);
  }
  if (relu) { accx = fmaxf(accx, 0.f); accy = fmaxf(accy, 0.f); }
  hb[(size_t)v * 64 + lane] = pack2(accx, accy);
}

// ---------------- launch ----------------
extern "C" void kernel_launch(void* const* d_in, const int* in_sizes, int n_in,
                              void* d_out, int out_size, void* d_ws, size_t ws_size,
                              hipStream_t stream) {
  const float* x     = (const float*)d_in[0];
  const float* query = (const float*)d_in[1];
  const int*   batch = (const int*)d_in[2];
  const int*   eidx  = (const int*)d_in[3];
  const float* W[4]  = {(const float*)d_in[4], (const float*)d_in[6],
                        (const float*)d_in[8], (const float*)d_in[10]};
  const float* bv[4] = {(const float*)d_in[5], (const float*)d_in[7],
                        (const float*)d_in[9], (const float*)d_in[11]};
  const float* Wc = (const float*)d_in[12];
  const float* bc = (const float*)d_in[13];
  float* out = (float*)d_out;

  const int n = in_sizes[2];       // 100000 (src packing needs n <= 131072)
  const int e = in_sizes[3] / 2;   // 1600000
  const int* fs = eidx;            // edge_index[0] = sources
  const int* fd = eidx + e;        // edge_index[1] = targets (aggregation index)

  char* p = (char*)d_ws;
  auto carve = [&](size_t bytes) -> void* {
    void* r = (void*)p;
    p += (bytes + 255) & ~(size_t)255;
    return r;
  };
  const int nscan = (n + 255) / 256;           // 391 (<= 512 for scanB)
  int*      cnt     = (int*)carve((size_t)n * 4);
  int*      off     = (int*)carve((size_t)(n + 1) * 4);
  int*      bsum    = (int*)carve((size_t)nscan * 4);
  int*      boff    = (int*)carve((size_t)nscan * 4);
  int*      rank    = (int*)carve((size_t)e * 4);
  float*    dis     = (float*)carve((size_t)n * 4);
  uint32_t* csr     = (uint32_t*)carve((size_t)e * 4);          // packed {src, w15}
  uint32_t* hb      = (uint32_t*)carve((size_t)n * 64 * 4);     // bf16 h (residual + GEMM in)
  uint8_t*  hw8     = (uint8_t*)carve((size_t)n * 128);         // fp8 h@W (gather src)

  const int eb = (e + 255) / 256;

  init_kernel<<<nscan, 256, 0, stream>>>(cnt, n);
  count_rank_kernel<<<eb, 256, 0, stream>>>(fd, cnt, rank, e);
  scanA_kernel<<<nscan, 256, 0, stream>>>(cnt, off, bsum, n);
  scanB_kernel<<<1, 512, 0, stream>>>(bsum, boff, nscan, off, n);
  scanC_kernel<<<nscan, 256, 0, stream>>>(off, boff, cnt, dis, n);
  fill_kernel<<<eb, 256, 0, stream>>>(fs, fd, rank, off, dis, csr, e);
  h0_kernel<<<(n * 64 + 255) / 256, 256, 0, stream>>>(x, query, batch, hb, n);

  const int gblk = (n + 255) / 256;
  for (int l = 0; l < 4; ++l) {
    mfma_gemm_kernel<128, 1><<<gblk, 256, 0, stream>>>(hb, W[l], nullptr, hw8, n);
    agg_kernel<<<(n + 3) / 4, 256, 0, stream>>>(hw8, hb, bv[l], off, csr,
                                                dis, (l < 3) ? 1 : 0, n);
  }
  mfma_gemm_kernel<64, 0><<<gblk, 256, 0, stream>>>(hb, Wc, bc, out, n);
}

// Round 10
// 458.996 us; speedup vs baseline: 12.4999x; 1.2169x over previous
//
#include <hip/hip_runtime.h>
#include <cstdint>
#include <cstddef>

// Lessons: (r5) hot atomic counters serialize — keep counters distributed.
// (r8) LDS-atomic agg + 1-block/CU = 10x loss. (r9) agg is LATENCY-bound, not
//      bytes-bound (fp8 halved FETCH, dur unchanged) -> r10: quarter-wave nodes
//      (16 lanes/node, 4 independent edge chains per wave for 4x MLP).

typedef short bf16x8 __attribute__((ext_vector_type(8)));
typedef float f32x4 __attribute__((ext_vector_type(4)));

// ---------------- bf16 helpers ----------------
static __device__ __forceinline__ uint32_t f2bf(float x) {
  uint32_t u = __float_as_uint(x);
  return (u + 0x7fffu + ((u >> 16) & 1u)) >> 16;  // RNE
}
static __device__ __forceinline__ uint32_t pack2(float a, float b) {
  return f2bf(a) | (f2bf(b) << 16);
}
static __device__ __forceinline__ float bf_lo(uint32_t u) { return __uint_as_float(u << 16); }
static __device__ __forceinline__ float bf_hi(uint32_t u) { return __uint_as_float(u & 0xffff0000u); }

// ---------------- Threefry-2x32-20, key (0,42) ----------------
static __device__ __forceinline__ uint32_t rotl32(uint32_t v, int d) {
  return (v << d) | (v >> (32 - d));
}

static __device__ __forceinline__ void threefry2x32(uint32_t k0, uint32_t k1,
                                                    uint32_t& x0, uint32_t& x1) {
  uint32_t k2 = k0 ^ k1 ^ 0x1BD11BDAu;
  x0 += k0; x1 += k1;
#define TF_R(r) { x0 += x1; x1 = rotl32(x1, (r)); x1 ^= x0; }
  TF_R(13) TF_R(15) TF_R(26) TF_R(6)
  x0 += k1; x1 += k2 + 1u;
  TF_R(17) TF_R(29) TF_R(16) TF_R(24)
  x0 += k2; x1 += k0 + 2u;
  TF_R(13) TF_R(15) TF_R(26) TF_R(6)
  x0 += k0; x1 += k1 + 3u;
  TF_R(17) TF_R(29) TF_R(16) TF_R(24)
  x0 += k1; x1 += k2 + 4u;
  TF_R(13) TF_R(15) TF_R(26) TF_R(6)
  x0 += k2; x1 += k0 + 5u;
#undef TF_R
}

// ---------------- graph preprocessing ----------------
__global__ void init_kernel(int* cnt, int n) {
  int i = blockIdx.x * blockDim.x + threadIdx.x;
  if (i < n) cnt[i] = 0;
}

__global__ void count_rank_kernel(const int* __restrict__ fd, int* __restrict__ cnt,
                                  int* __restrict__ rank, int e) {
  int i = blockIdx.x * blockDim.x + threadIdx.x;
  if (i < e) rank[i] = atomicAdd(&cnt[fd[i]], 1);
}

__global__ void scanA_kernel(const int* __restrict__ cnt, int* __restrict__ off,
                             int* __restrict__ bsum, int n) {
  __shared__ int s[256];
  int t = threadIdx.x;
  int i = blockIdx.x * 256 + t;
  int v = (i < n) ? cnt[i] : 0;
  s[t] = v;
  __syncthreads();
  for (int d = 1; d < 256; d <<= 1) {
    int add = (t >= d) ? s[t - d] : 0;
    __syncthreads();
    s[t] += add;
    __syncthreads();
  }
  if (i < n) off[i] = s[t] - v;  // exclusive
  if (t == 255) bsum[blockIdx.x] = s[255];
}

__global__ void scanB_kernel(const int* __restrict__ bsum, int* __restrict__ boff,
                             int nb, int* __restrict__ off, int n) {
  __shared__ int s[512];
  int t = threadIdx.x;
  int v = (t < nb) ? bsum[t] : 0;
  s[t] = v;
  __syncthreads();
  for (int d = 1; d < 512; d <<= 1) {
    int add = (t >= d) ? s[t - d] : 0;
    __syncthreads();
    s[t] += add;
    __syncthreads();
  }
  if (t < nb) boff[t] = s[t] - v;
  if (t == nb - 1) off[n] = s[t];  // total = E
}

__global__ void scanC_kernel(int* __restrict__ off, const int* __restrict__ boff,
                             const int* __restrict__ cnt, float* __restrict__ dis, int n) {
  int i = blockIdx.x * 256 + threadIdx.x;
  if (i < n) {
    off[i] += boff[blockIdx.x];
    dis[i] = 1.0f / sqrtf((float)(cnt[i] + 1));  // deg includes self-loop
  }
}

// atomic-free scatter; packed entry: src(17 bits) | bf16(w)[14:0] << 17  (w>0, <2)
__global__ void fill_kernel(const int* __restrict__ fs, const int* __restrict__ fd,
                            const int* __restrict__ rank, const int* __restrict__ off,
                            const float* __restrict__ dis,
                            uint32_t* __restrict__ csr, int e) {
  int i = blockIdx.x * blockDim.x + threadIdx.x;
  if (i < e) {
    int s = fs[i], d = fd[i];
    uint32_t w15 = f2bf(dis[s] * dis[d]) & 0x7fffu;
    csr[off[d] + rank[i]] = (uint32_t)s | (w15 << 17);
  }
}

// h0 = query[batch] * x -> bf16 hb (residual lives in bf16)
__global__ void h0_kernel(const float* __restrict__ x, const float* __restrict__ query,
                          const int* __restrict__ batch, uint32_t* __restrict__ hb, int n) {
  int i = blockIdx.x * blockDim.x + threadIdx.x;  // one bf16x2 word (2 cols)
  int total = n * 64;
  if (i < total) {
    int node = i >> 6;
    int w = i & 63;
    int b = batch[node];
    float2 xv = ((const float2*)x)[i];
    float2 qv = ((const float2*)query)[b * 64 + w];
    hb[i] = pack2(xv.x * qv.x, xv.y * qv.y);
  }
}

// ---------------- MFMA GEMM: C[nrows,BN] = A_bf16[nrows,128] @ W_f32[128,BN] ----------------
// W split into bf16 hi+lo -> two MFMAs per k-step give ~fp32-grade accuracy.
// OUT_MODE 1: write fp8 e4m3 bytes (gather source). OUT_MODE 0: fp32 +bias +fused dropout.
template<int BN, int OUT_MODE>
__global__ __launch_bounds__(256)
void mfma_gemm_kernel(const uint32_t* __restrict__ Abf,   // bf16x2 words, row stride 64
                      const float* __restrict__ Wm,       // fp32 [128][BN] row-major
                      const float* __restrict__ bias,     // nullptr or [BN]
                      void* __restrict__ Cout, int nrows) {
  constexpr int CT = BN / 16;
  __shared__ short Wt[2][BN][136];
  const int tid = threadIdx.x;

  for (int q = tid; q < (128 * BN) / 4; q += 256) {
    int el = q * 4;
    int k = el / BN;
    int col = el % BN;
    float4 w4 = *(const float4*)(Wm + el);
    float wv[4] = {w4.x, w4.y, w4.z, w4.w};
#pragma unroll
    for (int j = 0; j < 4; ++j) {
      uint32_t hi = f2bf(wv[j]);
      float hif = __uint_as_float(hi << 16);
      uint32_t lo = f2bf(wv[j] - hif);
      Wt[0][col + j][k] = (short)hi;
      Wt[1][col + j][k] = (short)lo;
    }
  }
  __syncthreads();

  const int wave = tid >> 6;
  const int lane = tid & 63;
  const int lrow = lane & 15;
  const int lk = lane >> 4;
  const int rowbase = blockIdx.x * 256 + wave * 64;
  const uint16_t* Au = (const uint16_t*)Abf;

  f32x4 acc[4][CT];
#pragma unroll
  for (int rt = 0; rt < 4; ++rt)
#pragma unroll
    for (int ct = 0; ct < CT; ++ct) acc[rt][ct] = (f32x4){0.f, 0.f, 0.f, 0.f};

#pragma unroll
  for (int s = 0; s < 4; ++s) {
    bf16x8 a[4];
#pragma unroll
    for (int rt = 0; rt < 4; ++rt) {
      int gr = rowbase + rt * 16 + lrow;
      int gra = (gr < nrows) ? gr : 0;
      a[rt] = *reinterpret_cast<const bf16x8*>(Au + (size_t)gra * 128 + s * 32 + lk * 8);
    }
#pragma unroll
    for (int ct = 0; ct < CT; ++ct) {
      bf16x8 bhi = *reinterpret_cast<const bf16x8*>(&Wt[0][ct * 16 + lrow][s * 32 + lk * 8]);
      bf16x8 blo = *reinterpret_cast<const bf16x8*>(&Wt[1][ct * 16 + lrow][s * 32 + lk * 8]);
#pragma unroll
      for (int rt = 0; rt < 4; ++rt)
        acc[rt][ct] = __builtin_amdgcn_mfma_f32_16x16x32_bf16(a[rt], bhi, acc[rt][ct], 0, 0, 0);
#pragma unroll
      for (int rt = 0; rt < 4; ++rt)
        acc[rt][ct] = __builtin_amdgcn_mfma_f32_16x16x32_bf16(a[rt], blo, acc[rt][ct], 0, 0, 0);
    }
  }

  // store: C/D mapping col=lane&15, row=(lane>>4)*4+reg
#pragma unroll
  for (int rt = 0; rt < 4; ++rt)
#pragma unroll
    for (int ct = 0; ct < CT; ++ct)
#pragma unroll
      for (int r = 0; r < 4; ++r) {
        int gr = rowbase + rt * 16 + lk * 4 + r;
        if (gr >= nrows) continue;
        int col = ct * 16 + lrow;
        float v = acc[rt][ct][r];
        if constexpr (OUT_MODE == 1) {
          uint32_t pk = __builtin_amdgcn_cvt_pk_fp8_f32(v, v, 0u, false);
          ((uint8_t*)Cout)[(size_t)gr * BN + col] = (uint8_t)pk;
        } else {
          v += bias[col];
          uint32_t x0 = 0u, x1 = (uint32_t)gr * (uint32_t)BN + (uint32_t)col;
          threefry2x32(0u, 42u, x0, x1);
          uint32_t bits = x0 ^ x1;
          float u = __uint_as_float((bits >> 9) | 0x3F800000u) - 1.0f;
          ((float*)Cout)[(size_t)gr * BN + col] = (u < 0.8f) ? (v / 0.8f) : 0.0f;
        }
      }
}

// ---------------- aggregation: QUARTER-WAVE per node (16 lanes, 8 fp8 elems/lane) ----------------
// 4 independent edge chains per wave64 -> ~4x memory-level parallelism vs 1 node/wave.
// hb[v] := maybe_relu( bias + hb[v](res,bf16) + dis^2*hw8[v] + sum_edges w*hw8[src] )
__global__ __launch_bounds__(256)
void agg_kernel(const uint8_t* __restrict__ hw8, uint32_t* __restrict__ hb,
                const float* __restrict__ bias,
                const int* __restrict__ off, const uint32_t* __restrict__ csr,
                const float* __restrict__ dis, int relu, int n) {
  const int v = (blockIdx.x * blockDim.x + threadIdx.x) >> 4;  // 16 nodes/block
  const int sl = threadIdx.x & 15;                              // sub-lane in group
  if (v >= n) return;

  const int eoff = sl * 8;  // this lane's 8 elements of the 128-wide row
  float dv = dis[v];
  float sw = dv * dv;
  uint2 self8 = *(const uint2*)(hw8 + (size_t)v * 128 + eoff);
  uint4 res4 = *(const uint4*)(hb + (size_t)v * 64 + sl * 4);
  float4 b0 = *(const float4*)(bias + eoff);
  float4 b1 = *(const float4*)(bias + eoff + 4);

  float acc[8];
  acc[0] = fmaf(sw, __builtin_amdgcn_cvt_f32_fp8(self8.x, 0), b0.x + bf_lo(res4.x));
  acc[1] = fmaf(sw, __builtin_amdgcn_cvt_f32_fp8(self8.x, 1), b0.y + bf_hi(res4.x));
  acc[2] = fmaf(sw, __builtin_amdgcn_cvt_f32_fp8(self8.x, 2), b0.z + bf_lo(res4.y));
  acc[3] = fmaf(sw, __builtin_amdgcn_cvt_f32_fp8(self8.x, 3), b0.w + bf_hi(res4.y));
  acc[4] = fmaf(sw, __builtin_amdgcn_cvt_f32_fp8(self8.y, 0), b1.x + bf_lo(res4.z));
  acc[5] = fmaf(sw, __builtin_amdgcn_cvt_f32_fp8(self8.y, 1), b1.y + bf_hi(res4.z));
  acc[6] = fmaf(sw, __builtin_amdgcn_cvt_f32_fp8(self8.y, 2), b1.z + bf_lo(res4.w));
  acc[7] = fmaf(sw, __builtin_amdgcn_cvt_f32_fp8(self8.y, 3), b1.w + bf_hi(res4.w));

#define EDGE_ACC(cw, rw)                                                     \
  {                                                                          \
    float w = __uint_as_float(((cw) >> 17) << 16);                           \
    acc[0] = fmaf(w, __builtin_amdgcn_cvt_f32_fp8((rw).x, 0), acc[0]);       \
    acc[1] = fmaf(w, __builtin_amdgcn_cvt_f32_fp8((rw).x, 1), acc[1]);       \
    acc[2] = fmaf(w, __builtin_amdgcn_cvt_f32_fp8((rw).x, 2), acc[2]);       \
    acc[3] = fmaf(w, __builtin_amdgcn_cvt_f32_fp8((rw).x, 3), acc[3]);       \
    acc[4] = fmaf(w, __builtin_amdgcn_cvt_f32_fp8((rw).y, 0), acc[4]);       \
    acc[5] = fmaf(w, __builtin_amdgcn_cvt_f32_fp8((rw).y, 1), acc[5]);       \
    acc[6] = fmaf(w, __builtin_amdgcn_cvt_f32_fp8((rw).y, 2), acc[6]);       \
    acc[7] = fmaf(w, __builtin_amdgcn_cvt_f32_fp8((rw).y, 3), acc[7]);       \
  }

  const int s0 = off[v], s1 = off[v + 1];
  int i = s0;
  for (; i + 8 <= s1; i += 8) {
    uint32_t c[8];
    uint2 r[8];
#pragma unroll
    for (int j = 0; j < 8; ++j) c[j] = csr[i + j];
#pragma unroll
    for (int j = 0; j < 8; ++j)
      r[j] = *(const uint2*)(hw8 + (size_t)(c[j] & 0x1ffffu) * 128 + eoff);
#pragma unroll
    for (int j = 0; j < 8; ++j) EDGE_ACC(c[j], r[j]);
  }
  if (i + 4 <= s1) {
    uint32_t c[4];
    uint2 r[4];
#pragma unroll
    for (int j = 0; j < 4; ++j) c[j] = csr[i + j];
#pragma unroll
    for (int j = 0; j < 4; ++j)
      r[j] = *(const uint2*)(hw8 + (size_t)(c[j] & 0x1ffffu) * 128 + eoff);
#pragma unroll
    for (int j = 0; j < 4; ++j) EDGE_ACC(c[j], r[j]);
    i += 4;
  }
  for (; i < s1; ++i) {
    uint32_t c = csr[i];
    uint2 r = *(const uint2*)(hw8 + (size_t)(c & 0x1ffffu) * 128 + eoff);
    EDGE_ACC(c, r);
  }
#undef EDGE_ACC

  if (relu) {
#pragma unroll
    for (int t = 0; t < 8; ++t) acc[t] = fmaxf(acc[t], 0.f);
  }
  uint4 o;
  o.x = pack2(acc[0], acc[1]);
  o.y = pack2(acc[2], acc[3]);
  o.z = pack2(acc[4], acc[5]);
  o.w = pack2(acc[6], acc[7]);
  *(uint4*)(hb + (size_t)v * 64 + sl * 4) = o;
}

// ---------------- launch ----------------
extern "C" void kernel_launch(void* const* d_in, const int* in_sizes, int n_in,
                              void* d_out, int out_size, void* d_ws, size_t ws_size,
                              hipStream_t stream) {
  const float* x     = (const float*)d_in[0];
  const float* query = (const float*)d_in[1];
  const int*   batch = (const int*)d_in[2];
  const int*   eidx  = (const int*)d_in[3];
  const float* W[4]  = {(const float*)d_in[4], (const float*)d_in[6],
                        (const float*)d_in[8], (const float*)d_in[10]};
  const float* bv[4] = {(const float*)d_in[5], (const float*)d_in[7],
                        (const float*)d_in[9], (const float*)d_in[11]};
  const float* Wc = (const float*)d_in[12];
  const float* bc = (const float*)d_in[13];
  float* out = (float*)d_out;

  const int n = in_sizes[2];       // 100000 (src packing needs n <= 131072)
  const int e = in_sizes[3] / 2;   // 1600000
  const int* fs = eidx;            // edge_index[0] = sources
  const int* fd = eidx + e;        // edge_index[1] = targets (aggregation index)

  char* p = (char*)d_ws;
  auto carve = [&](size_t bytes) -> void* {
    void* r = (void*)p;
    p += (bytes + 255) & ~(size_t)255;
    return r;
  };
  const int nscan = (n + 255) / 256;           // 391 (<= 512 for scanB)
  int*      cnt     = (int*)carve((size_t)n * 4);
  int*      off     = (int*)carve((size_t)(n + 1) * 4);
  int*      bsum    = (int*)carve((size_t)nscan * 4);
  int*      boff    = (int*)carve((size_t)nscan * 4);
  int*      rank    = (int*)carve((size_t)e * 4);
  float*    dis     = (float*)carve((size_t)n * 4);
  uint32_t* csr     = (uint32_t*)carve((size_t)e * 4);          // packed {src, w15}
  uint32_t* hb      = (uint32_t*)carve((size_t)n * 64 * 4);     // bf16 h (residual + GEMM in)
  uint8_t*  hw8     = (uint8_t*)carve((size_t)n * 128);         // fp8 h@W (gather src)

  const int eb = (e + 255) / 256;

  init_kernel<<<nscan, 256, 0, stream>>>(cnt, n);
  count_rank_kernel<<<eb, 256, 0, stream>>>(fd, cnt, rank, e);
  scanA_kernel<<<nscan, 256, 0, stream>>>(cnt, off, bsum, n);
  scanB_kernel<<<1, 512, 0, stream>>>(bsum, boff, nscan, off, n);
  scanC_kernel<<<nscan, 256, 0, stream>>>(off, boff, cnt, dis, n);
  fill_kernel<<<eb, 256, 0, stream>>>(fs, fd, rank, off, dis, csr, e);
  h0_kernel<<<(n * 64 + 255) / 256, 256, 0, stream>>>(x, query, batch, hb, n);

  const int gblk = (n + 255) / 256;
  for (int l = 0; l < 4; ++l) {
    mfma_gemm_kernel<128, 1><<<gblk, 256, 0, stream>>>(hb, W[l], nullptr, hw8, n);
    agg_kernel<<<(n * 16 + 255) / 256, 256, 0, stream>>>(hw8, hb, bv[l], off, csr,
                                                         dis, (l < 3) ? 1 : 0, n);
  }
  mfma_gemm_kernel<64, 0><<<gblk, 256, 0, stream>>>(hb, Wc, bc, out, n);
}

// Round 12
// 406.517 us; speedup vs baseline: 14.1136x; 1.1291x over previous
//
#include <hip/hip_runtime.h>
#include <cstdint>
#include <cstddef>

// Lessons: (r5) hot atomic counters serialize — keep counters distributed.
// (r8) LDS-atomic agg + 1-block/CU = 10x loss. (r9) agg is LATENCY-bound, not
// bytes-bound. (r10) 4x MLP via 16-lane nodes: agg 68->45us; count_rank = 67us
// of pure atomic-return stall (0.5% VALU) -> hide streaming work inside it.
// (r11) cvt_f32_fp8 selector must be a syntactic literal — no loop-indexed q&3.
// r12: 8-lane nodes (8 chains/wave), layer GEMMs single-bf16 W, h0 fused into
// count_rank's stall shadow; EDGE_ACC written with explicit constant selectors.

typedef short bf16x8 __attribute__((ext_vector_type(8)));
typedef float f32x4 __attribute__((ext_vector_type(4)));

// ---------------- bf16 helpers ----------------
static __device__ __forceinline__ uint32_t f2bf(float x) {
  uint32_t u = __float_as_uint(x);
  return (u + 0x7fffu + ((u >> 16) & 1u)) >> 16;  // RNE
}
static __device__ __forceinline__ uint32_t pack2(float a, float b) {
  return f2bf(a) | (f2bf(b) << 16);
}
static __device__ __forceinline__ float bf_lo(uint32_t u) { return __uint_as_float(u << 16); }
static __device__ __forceinline__ float bf_hi(uint32_t u) { return __uint_as_float(u & 0xffff0000u); }

// ---------------- Threefry-2x32-20, key (0,42) ----------------
static __device__ __forceinline__ uint32_t rotl32(uint32_t v, int d) {
  return (v << d) | (v >> (32 - d));
}

static __device__ __forceinline__ void threefry2x32(uint32_t k0, uint32_t k1,
                                                    uint32_t& x0, uint32_t& x1) {
  uint32_t k2 = k0 ^ k1 ^ 0x1BD11BDAu;
  x0 += k0; x1 += k1;
#define TF_R(r) { x0 += x1; x1 = rotl32(x1, (r)); x1 ^= x0; }
  TF_R(13) TF_R(15) TF_R(26) TF_R(6)
  x0 += k1; x1 += k2 + 1u;
  TF_R(17) TF_R(29) TF_R(16) TF_R(24)
  x0 += k2; x1 += k0 + 2u;
  TF_R(13) TF_R(15) TF_R(26) TF_R(6)
  x0 += k0; x1 += k1 + 3u;
  TF_R(17) TF_R(29) TF_R(16) TF_R(24)
  x0 += k1; x1 += k2 + 4u;
  TF_R(13) TF_R(15) TF_R(26) TF_R(6)
  x0 += k2; x1 += k0 + 5u;
#undef TF_R
}

// ---------------- graph preprocessing ----------------
__global__ void init_kernel(int* cnt, int n) {
  int i = blockIdx.x * blockDim.x + threadIdx.x;
  if (i < n) cnt[i] = 0;
}

// fused: blocks [0,eb) do count+rank (atomic-stall-bound); blocks [eb,..) do
// h0 = query[batch]*x -> bf16 hb (streams inside the atomic stall shadow).
__global__ void pre_kernel(const int* __restrict__ fd, int* __restrict__ cnt,
                           int* __restrict__ rank, int e, int eb,
                           const float* __restrict__ x, const float* __restrict__ query,
                           const int* __restrict__ batch, uint32_t* __restrict__ hb,
                           int n) {
  int b = blockIdx.x;
  if (b < eb) {
    int i = b * 256 + threadIdx.x;
    if (i < e) rank[i] = atomicAdd(&cnt[fd[i]], 1);
  } else {
    int i = (b - eb) * 256 + threadIdx.x;
    int total = n * 64;
    if (i < total) {
      int node = i >> 6;
      int w = i & 63;
      int bq = batch[node];
      float2 xv = ((const float2*)x)[i];
      float2 qv = ((const float2*)query)[bq * 64 + w];
      hb[i] = pack2(xv.x * qv.x, xv.y * qv.y);
    }
  }
}

__global__ void scanA_kernel(const int* __restrict__ cnt, int* __restrict__ off,
                             int* __restrict__ bsum, int n) {
  __shared__ int s[256];
  int t = threadIdx.x;
  int i = blockIdx.x * 256 + t;
  int v = (i < n) ? cnt[i] : 0;
  s[t] = v;
  __syncthreads();
  for (int d = 1; d < 256; d <<= 1) {
    int add = (t >= d) ? s[t - d] : 0;
    __syncthreads();
    s[t] += add;
    __syncthreads();
  }
  if (i < n) off[i] = s[t] - v;  // exclusive
  if (t == 255) bsum[blockIdx.x] = s[255];
}

__global__ void scanB_kernel(const int* __restrict__ bsum, int* __restrict__ boff,
                             int nb, int* __restrict__ off, int n) {
  __shared__ int s[512];
  int t = threadIdx.x;
  int v = (t < nb) ? bsum[t] : 0;
  s[t] = v;
  __syncthreads();
  for (int d = 1; d < 512; d <<= 1) {
    int add = (t >= d) ? s[t - d] : 0;
    __syncthreads();
    s[t] += add;
    __syncthreads();
  }
  if (t < nb) boff[t] = s[t] - v;
  if (t == nb - 1) off[n] = s[t];  // total = E
}

__global__ void scanC_kernel(int* __restrict__ off, const int* __restrict__ boff,
                             const int* __restrict__ cnt, float* __restrict__ dis, int n) {
  int i = blockIdx.x * 256 + threadIdx.x;
  if (i < n) {
    off[i] += boff[blockIdx.x];
    dis[i] = 1.0f / sqrtf((float)(cnt[i] + 1));  // deg includes self-loop
  }
}

// atomic-free scatter; packed entry: src(17 bits) | bf16(w)[14:0] << 17  (w>0, <2)
__global__ void fill_kernel(const int* __restrict__ fs, const int* __restrict__ fd,
                            const int* __restrict__ rank, const int* __restrict__ off,
                            const float* __restrict__ dis,
                            uint32_t* __restrict__ csr, int e) {
  int i = blockIdx.x * blockDim.x + threadIdx.x;
  if (i < e) {
    int s = fs[i], d = fd[i];
    uint32_t w15 = f2bf(dis[s] * dis[d]) & 0x7fffu;
    csr[off[d] + rank[i]] = (uint32_t)s | (w15 << 17);
  }
}

// ---------------- MFMA GEMM: C[nrows,BN] = A_bf16[nrows,128] @ W_f32[128,BN] ----------------
// WSPLIT==2: W as bf16 hi+lo (fp32-grade, classifier). WSPLIT==1: single bf16 W
// (layer GEMMs — output is fp8-quantized anyway, halves MFMA + LDS).
// OUT_MODE 1: fp8 e4m3 bytes. OUT_MODE 0: fp32 +bias +fused JAX dropout.
template<int BN, int OUT_MODE, int WSPLIT>
__global__ __launch_bounds__(256)
void mfma_gemm_kernel(const uint32_t* __restrict__ Abf,   // bf16x2 words, row stride 64
                      const float* __restrict__ Wm,       // fp32 [128][BN] row-major
                      const float* __restrict__ bias,     // nullptr or [BN]
                      void* __restrict__ Cout, int nrows) {
  constexpr int CT = BN / 16;
  __shared__ short Wt[WSPLIT][BN][136];
  const int tid = threadIdx.x;

  for (int q = tid; q < (128 * BN) / 4; q += 256) {
    int el = q * 4;
    int k = el / BN;
    int col = el % BN;
    float4 w4 = *(const float4*)(Wm + el);
    float wv[4] = {w4.x, w4.y, w4.z, w4.w};
#pragma unroll
    for (int j = 0; j < 4; ++j) {
      uint32_t hi = f2bf(wv[j]);
      Wt[0][col + j][k] = (short)hi;
      if constexpr (WSPLIT == 2) {
        float hif = __uint_as_float(hi << 16);
        Wt[1][col + j][k] = (short)f2bf(wv[j] - hif);
      }
    }
  }
  __syncthreads();

  const int wave = tid >> 6;
  const int lane = tid & 63;
  const int lrow = lane & 15;
  const int lk = lane >> 4;
  const int rowbase = blockIdx.x * 256 + wave * 64;
  const uint16_t* Au = (const uint16_t*)Abf;

  f32x4 acc[4][CT];
#pragma unroll
  for (int rt = 0; rt < 4; ++rt)
#pragma unroll
    for (int ct = 0; ct < CT; ++ct) acc[rt][ct] = (f32x4){0.f, 0.f, 0.f, 0.f};

#pragma unroll
  for (int s = 0; s < 4; ++s) {
    bf16x8 a[4];
#pragma unroll
    for (int rt = 0; rt < 4; ++rt) {
      int gr = rowbase + rt * 16 + lrow;
      int gra = (gr < nrows) ? gr : 0;
      a[rt] = *reinterpret_cast<const bf16x8*>(Au + (size_t)gra * 128 + s * 32 + lk * 8);
    }
#pragma unroll
    for (int ct = 0; ct < CT; ++ct) {
      bf16x8 bhi = *reinterpret_cast<const bf16x8*>(&Wt[0][ct * 16 + lrow][s * 32 + lk * 8]);
#pragma unroll
      for (int rt = 0; rt < 4; ++rt)
        acc[rt][ct] = __builtin_amdgcn_mfma_f32_16x16x32_bf16(a[rt], bhi, acc[rt][ct], 0, 0, 0);
      if constexpr (WSPLIT == 2) {
        bf16x8 blo = *reinterpret_cast<const bf16x8*>(&Wt[1][ct * 16 + lrow][s * 32 + lk * 8]);
#pragma unroll
        for (int rt = 0; rt < 4; ++rt)
          acc[rt][ct] = __builtin_amdgcn_mfma_f32_16x16x32_bf16(a[rt], blo, acc[rt][ct], 0, 0, 0);
      }
    }
  }

  // store: C/D mapping col=lane&15, row=(lane>>4)*4+reg
#pragma unroll
  for (int rt = 0; rt < 4; ++rt)
#pragma unroll
    for (int ct = 0; ct < CT; ++ct)
#pragma unroll
      for (int r = 0; r < 4; ++r) {
        int gr = rowbase + rt * 16 + lk * 4 + r;
        if (gr >= nrows) continue;
        int col = ct * 16 + lrow;
        float v = acc[rt][ct][r];
        if constexpr (OUT_MODE == 1) {
          uint32_t pk = __builtin_amdgcn_cvt_pk_fp8_f32(v, v, 0u, false);
          ((uint8_t*)Cout)[(size_t)gr * BN + col] = (uint8_t)pk;
        } else {
          v += bias[col];
          uint32_t x0 = 0u, x1 = (uint32_t)gr * (uint32_t)BN + (uint32_t)col;
          threefry2x32(0u, 42u, x0, x1);
          uint32_t bits = x0 ^ x1;
          float u = __uint_as_float((bits >> 9) | 0x3F800000u) - 1.0f;
          ((float*)Cout)[(size_t)gr * BN + col] = (u < 0.8f) ? (v / 0.8f) : 0.0f;
        }
      }
}

// decode one fp8x4 word into 4 accs with literal selectors
#define CVT4(acc0, acc1, acc2, acc3, w, word)                                  \
  acc0 = fmaf(w, __builtin_amdgcn_cvt_f32_fp8((word), 0), acc0);               \
  acc1 = fmaf(w, __builtin_amdgcn_cvt_f32_fp8((word), 1), acc1);               \
  acc2 = fmaf(w, __builtin_amdgcn_cvt_f32_fp8((word), 2), acc2);               \
  acc3 = fmaf(w, __builtin_amdgcn_cvt_f32_fp8((word), 3), acc3);

// full 16-elem accumulate from a uint4 of fp8 (explicit literal selectors)
#define EDGE_ACC(cw, R)                                                        \
  {                                                                            \
    float w = __uint_as_float(((cw) >> 17) << 16);                             \
    CVT4(acc[0], acc[1], acc[2], acc[3], w, (R).x)                             \
    CVT4(acc[4], acc[5], acc[6], acc[7], w, (R).y)                             \
    CVT4(acc[8], acc[9], acc[10], acc[11], w, (R).z)                           \
    CVT4(acc[12], acc[13], acc[14], acc[15], w, (R).w)                         \
  }

// ---------------- aggregation: EIGHTH-WAVE per node (8 lanes, 16 fp8 elems/lane) ----------------
// 8 independent edge chains per wave64 -> 2x MLP vs r10; same total VALU + bytes.
__global__ __launch_bounds__(256)
void agg_kernel(const uint8_t* __restrict__ hw8, uint32_t* __restrict__ hb,
                const float* __restrict__ bias,
                const int* __restrict__ off, const uint32_t* __restrict__ csr,
                const float* __restrict__ dis, int relu, int n) {
  const int v = (blockIdx.x * blockDim.x + threadIdx.x) >> 3;  // 32 nodes/block
  const int sl = threadIdx.x & 7;
  if (v >= n) return;

  const int eoff = sl * 16;  // this lane's 16 elements of the 128-wide row
  float dv = dis[v];
  float sw = dv * dv;
  uint4 selfw = *(const uint4*)(hw8 + (size_t)v * 128 + eoff);
  uint4 resA = *(const uint4*)(hb + (size_t)v * 64 + sl * 8);
  uint4 resB = *(const uint4*)(hb + (size_t)v * 64 + sl * 8 + 4);
  const float* bb = bias + eoff;

  float acc[16];
  acc[0]  = bb[0]  + bf_lo(resA.x);
  acc[1]  = bb[1]  + bf_hi(resA.x);
  acc[2]  = bb[2]  + bf_lo(resA.y);
  acc[3]  = bb[3]  + bf_hi(resA.y);
  acc[4]  = bb[4]  + bf_lo(resA.z);
  acc[5]  = bb[5]  + bf_hi(resA.z);
  acc[6]  = bb[6]  + bf_lo(resA.w);
  acc[7]  = bb[7]  + bf_hi(resA.w);
  acc[8]  = bb[8]  + bf_lo(resB.x);
  acc[9]  = bb[9]  + bf_hi(resB.x);
  acc[10] = bb[10] + bf_lo(resB.y);
  acc[11] = bb[11] + bf_hi(resB.y);
  acc[12] = bb[12] + bf_lo(resB.z);
  acc[13] = bb[13] + bf_hi(resB.z);
  acc[14] = bb[14] + bf_lo(resB.w);
  acc[15] = bb[15] + bf_hi(resB.w);
  // self-loop term with literal selectors
  CVT4(acc[0], acc[1], acc[2], acc[3], sw, selfw.x)
  CVT4(acc[4], acc[5], acc[6], acc[7], sw, selfw.y)
  CVT4(acc[8], acc[9], acc[10], acc[11], sw, selfw.z)
  CVT4(acc[12], acc[13], acc[14], acc[15], sw, selfw.w)

  const int s0 = off[v], s1 = off[v + 1];
  int i = s0;
  for (; i + 8 <= s1; i += 8) {
    uint32_t c[8];
    uint4 r[8];
#pragma unroll
    for (int j = 0; j < 8; ++j) c[j] = csr[i + j];
#pragma unroll
    for (int j = 0; j < 8; ++j)
      r[j] = *(const uint4*)(hw8 + (size_t)(c[j] & 0x1ffffu) * 128 + eoff);
    EDGE_ACC(c[0], r[0]) EDGE_ACC(c[1], r[1]) EDGE_ACC(c[2], r[2]) EDGE_ACC(c[3], r[3])
    EDGE_ACC(c[4], r[4]) EDGE_ACC(c[5], r[5]) EDGE_ACC(c[6], r[6]) EDGE_ACC(c[7], r[7])
  }
  if (i + 4 <= s1) {
    uint32_t c[4];
    uint4 r[4];
#pragma unroll
    for (int j = 0; j < 4; ++j) c[j] = csr[i + j];
#pragma unroll
    for (int j = 0; j < 4; ++j)
      r[j] = *(const uint4*)(hw8 + (size_t)(c[j] & 0x1ffffu) * 128 + eoff);
    EDGE_ACC(c[0], r[0]) EDGE_ACC(c[1], r[1]) EDGE_ACC(c[2], r[2]) EDGE_ACC(c[3], r[3])
    i += 4;
  }
  for (; i < s1; ++i) {
    uint32_t c = csr[i];
    uint4 r = *(const uint4*)(hw8 + (size_t)(c & 0x1ffffu) * 128 + eoff);
    EDGE_ACC(c, r)
  }

  if (relu) {
#pragma unroll
    for (int t = 0; t < 16; ++t) acc[t] = fmaxf(acc[t], 0.f);
  }
  uint4 oA, oB;
  oA.x = pack2(acc[0], acc[1]);
  oA.y = pack2(acc[2], acc[3]);
  oA.z = pack2(acc[4], acc[5]);
  oA.w = pack2(acc[6], acc[7]);
  oB.x = pack2(acc[8], acc[9]);
  oB.y = pack2(acc[10], acc[11]);
  oB.z = pack2(acc[12], acc[13]);
  oB.w = pack2(acc[14], acc[15]);
  *(uint4*)(hb + (size_t)v * 64 + sl * 8) = oA;
  *(uint4*)(hb + (size_t)v * 64 + sl * 8 + 4) = oB;
}
#undef EDGE_ACC
#undef CVT4

// ---------------- launch ----------------
extern "C" void kernel_launch(void* const* d_in, const int* in_sizes, int n_in,
                              void* d_out, int out_size, void* d_ws, size_t ws_size,
                              hipStream_t stream) {
  const float* x     = (const float*)d_in[0];
  const float* query = (const float*)d_in[1];
  const int*   batch = (const int*)d_in[2];
  const int*   eidx  = (const int*)d_in[3];
  const float* W[4]  = {(const float*)d_in[4], (const float*)d_in[6],
                        (const float*)d_in[8], (const float*)d_in[10]};
  const float* bv[4] = {(const float*)d_in[5], (const float*)d_in[7],
                        (const float*)d_in[9], (const float*)d_in[11]};
  const float* Wc = (const float*)d_in[12];
  const float* bc = (const float*)d_in[13];
  float* out = (float*)d_out;

  const int n = in_sizes[2];       // 100000 (src packing needs n <= 131072)
  const int e = in_sizes[3] / 2;   // 1600000
  const int* fs = eidx;            // edge_index[0] = sources
  const int* fd = eidx + e;        // edge_index[1] = targets (aggregation index)

  char* p = (char*)d_ws;
  auto carve = [&](size_t bytes) -> void* {
    void* r = (void*)p;
    p += (bytes + 255) & ~(size_t)255;
    return r;
  };
  const int nscan = (n + 255) / 256;           // 391 (<= 512 for scanB)
  int*      cnt     = (int*)carve((size_t)n * 4);
  int*      off     = (int*)carve((size_t)(n + 1) * 4);
  int*      bsum    = (int*)carve((size_t)nscan * 4);
  int*      boff    = (int*)carve((size_t)nscan * 4);
  int*      rank    = (int*)carve((size_t)e * 4);
  float*    dis     = (float*)carve((size_t)n * 4);
  uint32_t* csr     = (uint32_t*)carve((size_t)e * 4);          // packed {src, w15}
  uint32_t* hb      = (uint32_t*)carve((size_t)n * 64 * 4);     // bf16 h (residual + GEMM in)
  uint8_t*  hw8     = (uint8_t*)carve((size_t)n * 128);         // fp8 h@W (gather src)

  const int eb = (e + 255) / 256;
  const int h0b = (n * 64 + 255) / 256;

  init_kernel<<<nscan, 256, 0, stream>>>(cnt, n);
  pre_kernel<<<eb + h0b, 256, 0, stream>>>(fd, cnt, rank, e, eb, x, query, batch, hb, n);
  scanA_kernel<<<nscan, 256, 0, stream>>>(cnt, off, bsum, n);
  scanB_kernel<<<1, 512, 0, stream>>>(bsum, boff, nscan, off, n);
  scanC_kernel<<<nscan, 256, 0, stream>>>(off, boff, cnt, dis, n);
  fill_kernel<<<eb, 256, 0, stream>>>(fs, fd, rank, off, dis, csr, e);

  const int gblk = (n + 255) / 256;
  for (int l = 0; l < 4; ++l) {
    mfma_gemm_kernel<128, 1, 1><<<gblk, 256, 0, stream>>>(hb, W[l], nullptr, hw8, n);
    agg_kernel<<<(n * 8 + 255) / 256, 256, 0, stream>>>(hw8, hb, bv[l], off, csr,
                                                        dis, (l < 3) ? 1 : 0, n);
  }
  mfma_gemm_kernel<64, 0, 2><<<gblk, 256, 0, stream>>>(hb, Wc, bc, out, n);
}